// Round 5
// baseline (260.802 us; speedup 1.0000x reference)
//
#include <hip/hip_runtime.h>

#define NN 100000
#define SS 50000
#define KK 32
#define CC 128
#define PCHUNK 5   // chunks (16 rows) per proj block; 1250 * 5 * 16 = 100000

typedef _Float16 f16x8 __attribute__((ext_vector_type(8)));
typedef _Float16 f16x4 __attribute__((ext_vector_type(4)));
typedef _Float16 f16x2 __attribute__((ext_vector_type(2)));
typedef float f32x4 __attribute__((ext_vector_type(4)));

// Workspace table T: per row i (512 B stride, 256 halfs):
//   T[i*256 +   0 .. 127] = fp16(word_vec[i])   (proj_kernel, wave 0)
//   T[i*256 + 128 .. 255] = fp16(P[i])          (proj_kernel epilogue)

// ---------------------------------------------------------------------------
// Kernel 1 (fused convert+proj): P = leaky_relu(wv @ W^T + b) via
// mfma_f32_16x16x32_f16. A read from wv fp32, converted in regs; wave 0 also
// stores the fp16 wv copy into T. B-frags register-resident, 5 chunks/block.
// ---------------------------------------------------------------------------
__global__ __launch_bounds__(256) void proj_kernel(
    const float* __restrict__ wv,
    const float* __restrict__ W,
    const float* __restrict__ bias,
    _Float16* __restrict__ T,
    float* __restrict__ out)
{
    const int w = threadIdx.x >> 6;
    const int l = threadIdx.x & 63;
    const int q = l >> 4;      // quad 0..3
    const int c = l & 15;

    // B-frags: B[k][n] = W[n][k]; lane holds n = w*32+nch*16+c,
    // k = kc*32 + q*8 + j.
    f16x8 bf[2][4];
    float bo[2];
    #pragma unroll
    for (int nch = 0; nch < 2; nch++) {
        const int n = w * 32 + nch * 16 + c;
        bo[nch] = bias[n];
        const float* Wr = W + (size_t)n * CC;
        #pragma unroll
        for (int kc = 0; kc < 4; kc++) {
            const int k0 = kc * 32 + q * 8;
            const float4 w0 = *(const float4*)(Wr + k0);
            const float4 w1 = *(const float4*)(Wr + k0 + 4);
            f16x8 b;
            b[0] = (_Float16)w0.x; b[1] = (_Float16)w0.y;
            b[2] = (_Float16)w0.z; b[3] = (_Float16)w0.w;
            b[4] = (_Float16)w1.x; b[5] = (_Float16)w1.y;
            b[6] = (_Float16)w1.z; b[7] = (_Float16)w1.w;
            bf[nch][kc] = b;
        }
    }

    for (int i = 0; i < PCHUNK; i++) {
        const int m0 = (blockIdx.x * PCHUNK + i) * 16;
        const float* Ar = wv + (size_t)(m0 + c) * CC + q * 8;

        // A-frags straight from fp32 wv (batched loads, convert in regs)
        f16x8 af[4];
        #pragma unroll
        for (int kc = 0; kc < 4; kc++) {
            const float4 a0 = *(const float4*)(Ar + kc * 32);
            const float4 a1 = *(const float4*)(Ar + kc * 32 + 4);
            f16x8 a;
            a[0] = (_Float16)a0.x; a[1] = (_Float16)a0.y;
            a[2] = (_Float16)a0.z; a[3] = (_Float16)a0.w;
            a[4] = (_Float16)a1.x; a[5] = (_Float16)a1.y;
            a[6] = (_Float16)a1.z; a[7] = (_Float16)a1.w;
            af[kc] = a;
        }

        // wave 0 publishes the fp16 wv copy (dense 16B stores)
        if (w == 0) {
            _Float16* Tw = T + (size_t)(m0 + c) * 256 + q * 8;
            #pragma unroll
            for (int kc = 0; kc < 4; kc++)
                *(f16x8*)(Tw + kc * 32) = af[kc];
        }

        f32x4 acc[2] = {{0.f, 0.f, 0.f, 0.f}, {0.f, 0.f, 0.f, 0.f}};
        #pragma unroll
        for (int kc = 0; kc < 4; kc++) {
            acc[0] = __builtin_amdgcn_mfma_f32_16x16x32_f16(af[kc], bf[0][kc], acc[0], 0, 0, 0);
            acc[1] = __builtin_amdgcn_mfma_f32_16x16x32_f16(af[kc], bf[1][kc], acc[1], 0, 0, 0);
        }

        // D layout: col = c (+tile offset), row = q*4 + reg.
        #pragma unroll
        for (int nch = 0; nch < 2; nch++) {
            const int col = w * 32 + nch * 16 + c;
            #pragma unroll
            for (int r = 0; r < 4; r++) {
                const int row = m0 + q * 4 + r;
                float v = acc[nch][r] + bo[nch];
                v = v > 0.f ? v : 0.2f * v;
                out[(size_t)row * CC + col] = v;
                T[(size_t)row * 256 + 128 + col] = (_Float16)v;
            }
        }
    }
}

// ---------------------------------------------------------------------------
// Kernel 2: one wave per s, lane = r*16+c. ALL gathers unconditional and
// batched (restores memory-level parallelism -- the R4 bottleneck was
// per-gather vmcnt(0) serialization inside mask branches). Masked neighbors
// are handled arithmetically: sc=-1e6 -> p==+0.0 -> contributes 0.
// ---------------------------------------------------------------------------
__global__ __launch_bounds__(256) void attn_kernel(
    const _Float16* __restrict__ T,
    const int* __restrict__ src_idx,
    const int* __restrict__ neighs,
    const int* __restrict__ mask,
    float* __restrict__ out)
{
    const int s = (blockIdx.x * 256 + threadIdx.x) >> 6;
    if (s >= SS) return;
    const int lane = threadIdx.x & 63;
    const int c = lane & 15;
    const int r = lane >> 4;

    // prefetch neighbor ids + masks (issued first, everything depends on them)
    int nbv[8], mv[8];
    #pragma unroll
    for (int ch = 0; ch < 8; ch++) {
        nbv[ch] = neighs[s * KK + ch * 4 + r];
        mv[ch]  = mask[s * KK + ch * 4 + r];
    }
    const int src = src_idx[s];
    const f16x8 qh = *(const f16x8*)(T + (size_t)src * 256 + c * 8);

    // batched unconditional score-row gathers: 8 outstanding loads
    f16x8 kh[8];
    #pragma unroll
    for (int ch = 0; ch < 8; ch++)
        kh[ch] = *(const f16x8*)(T + (size_t)nbv[ch] * 256 + c * 8);

    float sc[8];
    #pragma unroll
    for (int ch = 0; ch < 8; ch++) {
        float d = 0.f;
        #pragma unroll
        for (int j = 0; j < 4; j++) {
            f16x2 qa; qa[0] = qh[2 * j];     qa[1] = qh[2 * j + 1];
            f16x2 ka; ka[0] = kh[ch][2 * j]; ka[1] = kh[ch][2 * j + 1];
            d = __builtin_amdgcn_fdot2(qa, ka, d, false);
        }
        d += __shfl_xor(d, 1);
        d += __shfl_xor(d, 2);
        d += __shfl_xor(d, 4);
        d += __shfl_xor(d, 8);
        sc[ch] = (mv[ch] == 1) ? d * 5.0f : -1e6f;
    }

    // softmax over 32 (8 regs x 4 r-groups). All-masked s -> uniform 1/32,
    // matching the reference exactly.
    float mx = sc[0];
    #pragma unroll
    for (int ch = 1; ch < 8; ch++) mx = fmaxf(mx, sc[ch]);
    mx = fmaxf(mx, __shfl_xor(mx, 16));
    mx = fmaxf(mx, __shfl_xor(mx, 32));

    float p[8];
    float sum = 0.f;
    #pragma unroll
    for (int ch = 0; ch < 8; ch++) {
        p[ch] = __expf(sc[ch] - mx);   // masked: exp(-1e6 - mx) == +0.0f
        sum += p[ch];
    }
    sum += __shfl_xor(sum, 16);
    sum += __shfl_xor(sum, 32);
    const float inv = 1.0f / sum;
    #pragma unroll
    for (int ch = 0; ch < 8; ch++) p[ch] *= inv;

    // aggregation: lane owns output cols [2*lane, 2*lane+1].
    // 2 batches of 16 gathers, loads hoisted ahead of the FMA chain.
    float ax = 0.f, ay = 0.f, bx = 0.f, by = 0.f;
    #pragma unroll
    for (int g = 0; g < 2; g++) {
        f16x2 vv[16];
        float pj[16];
        #pragma unroll
        for (int j = 0; j < 16; j++) {
            const int jj = g * 16 + j;
            const int idx = __shfl(nbv[jj >> 2], (jj & 3) << 4);
            pj[j] = __shfl(p[jj >> 2], (jj & 3) << 4);
            vv[j] = *(const f16x2*)(T + (size_t)idx * 256 + 128 + lane * 2);
        }
        #pragma unroll
        for (int j = 0; j < 16; j += 2) {
            ax += pj[j] * (float)vv[j][0];
            ay += pj[j] * (float)vv[j][1];
            bx += pj[j + 1] * (float)vv[j + 1][0];
            by += pj[j + 1] * (float)vv[j + 1][1];
        }
    }
    *((float2*)(out + (size_t)src * CC) + lane) = make_float2(ax + bx, ay + by);
}

extern "C" void kernel_launch(void* const* d_in, const int* in_sizes, int n_in,
                              void* d_out, int out_size, void* d_ws, size_t ws_size,
                              hipStream_t stream)
{
    const float* wv   = (const float*)d_in[0];
    const int*   src  = (const int*)d_in[1];
    const int*   nei  = (const int*)d_in[2];
    const int*   msk  = (const int*)d_in[3];
    const float* W    = (const float*)d_in[4];
    const float* bias = (const float*)d_in[5];
    float* out = (float*)d_out;
    _Float16* T = (_Float16*)d_ws;   // 100000 * 512 B = 51.2 MB

    proj_kernel<<<NN / (16 * PCHUNK), 256, 0, stream>>>(wv, W, bias, T, out); // 1250
    attn_kernel<<<(SS * 64) / 256, 256, 0, stream>>>(T, src, nei, msk, out);  // 12500
}

// Round 6
// 180.332 us; speedup vs baseline: 1.4462x; 1.4462x over previous
//
#include <hip/hip_runtime.h>

#define NN 100000
#define SS 50000
#define KK 32
#define CC 128
#define RPB 160          // rows per proj block; 625 * 160 = 100000
#define LDA 136          // LDS row stride in halfs (272 B = 17*16, b128-aligned)

typedef _Float16 f16x8 __attribute__((ext_vector_type(8)));
typedef _Float16 f16x4 __attribute__((ext_vector_type(4)));
typedef _Float16 f16x2 __attribute__((ext_vector_type(2)));
typedef float f32x4 __attribute__((ext_vector_type(4)));

// Workspace table T: per row i (512 B stride, 256 halfs):
//   T[i*256 +   0 .. 127] = fp16(word_vec[i])   (proj staging loop)
//   T[i*256 + 128 .. 255] = fp16(P[i])          (proj epilogue)

// ---------------------------------------------------------------------------
// Kernel 1 (fused convert+proj): P = leaky_relu(wv @ W^T + b) via
// mfma_f32_16x16x32_f16. 160 rows/block staged once into LDS (fp16, padded)
// with coalesced float4 loads; same loop publishes the fp16 wv copy to T.
// A-frags then come from LDS (broadcast -- kills the 4x redundant HBM A-reads
// that plagued R3-R5). B-frags register-resident per wave (32 cols each).
// ---------------------------------------------------------------------------
__global__ __launch_bounds__(256) void proj_kernel(
    const float* __restrict__ wv,
    const float* __restrict__ W,
    const float* __restrict__ bias,
    _Float16* __restrict__ T,
    float* __restrict__ out)
{
    __shared__ _Float16 sA[RPB][LDA];

    const int t = threadIdx.x;
    const int base = blockIdx.x * RPB;

    // Stage A (160 x 128 fp32 -> fp16 LDS + T copy). 20 float4 per thread.
    #pragma unroll 4
    for (int i = 0; i < 20; i++) {
        const int idx = i * 256 + t;
        const int row = idx >> 5;
        const int c4 = (idx & 31) * 4;
        const float4 v = *(const float4*)(wv + (size_t)(base + row) * CC + c4);
        f16x4 h;
        h[0] = (_Float16)v.x; h[1] = (_Float16)v.y;
        h[2] = (_Float16)v.z; h[3] = (_Float16)v.w;
        *(f16x4*)&sA[row][c4] = h;
        *(f16x4*)(T + (size_t)(base + row) * 256 + c4) = h;
    }

    const int w = t >> 6;
    const int l = t & 63;
    const int q = l >> 4;      // quad 0..3
    const int c = l & 15;

    // B-frags: B[k][n] = W[n][k]; lane holds n = w*32+nch*16+c, k = kc*32+q*8+j
    f16x8 bf[2][4];
    float bo[2];
    #pragma unroll
    for (int nch = 0; nch < 2; nch++) {
        const int n = w * 32 + nch * 16 + c;
        bo[nch] = bias[n];
        const float* Wr = W + (size_t)n * CC;
        #pragma unroll
        for (int kc = 0; kc < 4; kc++) {
            const int k0 = kc * 32 + q * 8;
            const float4 w0 = *(const float4*)(Wr + k0);
            const float4 w1 = *(const float4*)(Wr + k0 + 4);
            f16x8 b;
            b[0] = (_Float16)w0.x; b[1] = (_Float16)w0.y;
            b[2] = (_Float16)w0.z; b[3] = (_Float16)w0.w;
            b[4] = (_Float16)w1.x; b[5] = (_Float16)w1.y;
            b[6] = (_Float16)w1.z; b[7] = (_Float16)w1.w;
            bf[nch][kc] = b;
        }
    }
    __syncthreads();

    #pragma unroll 2
    for (int sub = 0; sub < RPB / 16; sub++) {
        const int rl = sub * 16 + c;

        f16x8 af[4];
        #pragma unroll
        for (int kc = 0; kc < 4; kc++)
            af[kc] = *(const f16x8*)&sA[rl][kc * 32 + q * 8];

        f32x4 acc[2] = {{0.f, 0.f, 0.f, 0.f}, {0.f, 0.f, 0.f, 0.f}};
        #pragma unroll
        for (int kc = 0; kc < 4; kc++) {
            acc[0] = __builtin_amdgcn_mfma_f32_16x16x32_f16(af[kc], bf[0][kc], acc[0], 0, 0, 0);
            acc[1] = __builtin_amdgcn_mfma_f32_16x16x32_f16(af[kc], bf[1][kc], acc[1], 0, 0, 0);
        }

        // D layout: col = c (+tile offset), row = q*4 + reg.
        #pragma unroll
        for (int nch = 0; nch < 2; nch++) {
            const int col = w * 32 + nch * 16 + c;
            #pragma unroll
            for (int r = 0; r < 4; r++) {
                const int row = base + sub * 16 + q * 4 + r;
                float v = acc[nch][r] + bo[nch];
                v = v > 0.f ? v : 0.2f * v;
                out[(size_t)row * CC + col] = v;
                T[(size_t)row * 256 + 128 + col] = (_Float16)v;
            }
        }
    }
}

// ---------------------------------------------------------------------------
// Kernel 2: one wave per s, lane = r*16+c. All gathers batched AND mask-
// skipped via address redirect (masked -> src row, L1-hot, no new lines;
// garbage values are arithmetically discarded). Agg phase: lane (r,c)
// gathers f16x8 of the rows whose probs it already holds -- zero broadcasts;
// cross-group butterfly then a fully-contiguous 512 B row store.
// ---------------------------------------------------------------------------
__global__ __launch_bounds__(256) void attn_kernel(
    const _Float16* __restrict__ T,
    const int* __restrict__ src_idx,
    const int* __restrict__ neighs,
    const int* __restrict__ mask,
    float* __restrict__ out)
{
    const int s = (blockIdx.x * 256 + threadIdx.x) >> 6;
    if (s >= SS) return;
    const int lane = threadIdx.x & 63;
    const int c = lane & 15;
    const int r = lane >> 4;

    int nbv[8], mv[8];
    #pragma unroll
    for (int ch = 0; ch < 8; ch++) {
        nbv[ch] = neighs[s * KK + ch * 4 + r];
        mv[ch]  = mask[s * KK + ch * 4 + r];
    }
    const int src = src_idx[s];
    const f16x8 qh = *(const f16x8*)(T + (size_t)src * 256 + c * 8);

    // Score gathers: batched, masked rows redirected to src (no new lines).
    f16x8 kh[8];
    #pragma unroll
    for (int ch = 0; ch < 8; ch++) {
        const int row = (mv[ch] == 1) ? nbv[ch] : src;
        kh[ch] = *(const f16x8*)(T + (size_t)row * 256 + c * 8);
    }

    float sc[8];
    #pragma unroll
    for (int ch = 0; ch < 8; ch++) {
        float d = 0.f;
        #pragma unroll
        for (int j = 0; j < 4; j++) {
            f16x2 qa; qa[0] = qh[2 * j];     qa[1] = qh[2 * j + 1];
            f16x2 ka; ka[0] = kh[ch][2 * j]; ka[1] = kh[ch][2 * j + 1];
            d = __builtin_amdgcn_fdot2(qa, ka, d, false);
        }
        d += __shfl_xor(d, 1);
        d += __shfl_xor(d, 2);
        d += __shfl_xor(d, 4);
        d += __shfl_xor(d, 8);
        sc[ch] = (mv[ch] == 1) ? d * 5.0f : -1e6f;
    }

    // Softmax over 32 (8 regs x 4 r-groups). All-masked s -> uniform 1/32,
    // matching the reference exactly.
    float mx = sc[0];
    #pragma unroll
    for (int ch = 1; ch < 8; ch++) mx = fmaxf(mx, sc[ch]);
    mx = fmaxf(mx, __shfl_xor(mx, 16));
    mx = fmaxf(mx, __shfl_xor(mx, 32));

    float p[8];
    float sum = 0.f;
    #pragma unroll
    for (int ch = 0; ch < 8; ch++) {
        p[ch] = __expf(sc[ch] - mx);   // masked: exp(-1e6 - mx) == +0.0f
        sum += p[ch];
    }
    sum += __shfl_xor(sum, 16);
    sum += __shfl_xor(sum, 32);
    const float inv = 1.0f / sum;
    #pragma unroll
    for (int ch = 0; ch < 8; ch++) p[ch] *= inv;

    // Agg gathers: lane (r,c) reads cols [c*8, c*8+8) of the 8 rows whose
    // probs it owns. Zero-prob rows redirected to src (hot, contributes 0).
    f16x8 vv[8];
    #pragma unroll
    for (int ch = 0; ch < 8; ch++) {
        const int row = (p[ch] != 0.f) ? nbv[ch] : src;
        vv[ch] = *(const f16x8*)(T + (size_t)row * 256 + 128 + c * 8);
    }

    float acc[8] = {0.f, 0.f, 0.f, 0.f, 0.f, 0.f, 0.f, 0.f};
    #pragma unroll
    for (int ch = 0; ch < 8; ch++) {
        #pragma unroll
        for (int j = 0; j < 8; j++)
            acc[j] += p[ch] * (float)vv[ch][j];
    }

    // Cross-group butterfly: sum the 4 r-group partials.
    #pragma unroll
    for (int j = 0; j < 8; j++) {
        acc[j] += __shfl_xor(acc[j], 16);
        acc[j] += __shfl_xor(acc[j], 32);
    }

    // lane (r,c) writes cols c*8 + r*2 + {0,1}: contiguous 512 B per wave.
    *((float2*)(out + (size_t)src * CC) + c * 4 + r) =
        make_float2(acc[r * 2], acc[r * 2 + 1]);
}

extern "C" void kernel_launch(void* const* d_in, const int* in_sizes, int n_in,
                              void* d_out, int out_size, void* d_ws, size_t ws_size,
                              hipStream_t stream)
{
    const float* wv   = (const float*)d_in[0];
    const int*   src  = (const int*)d_in[1];
    const int*   nei  = (const int*)d_in[2];
    const int*   msk  = (const int*)d_in[3];
    const float* W    = (const float*)d_in[4];
    const float* bias = (const float*)d_in[5];
    float* out = (float*)d_out;
    _Float16* T = (_Float16*)d_ws;   // 100000 * 512 B = 51.2 MB

    proj_kernel<<<NN / RPB, 256, 0, stream>>>(wv, W, bias, T, out);           // 625
    attn_kernel<<<(SS * 64) / 256, 256, 0, stream>>>(T, src, nei, msk, out);  // 12500
}